// Round 9
// baseline (378.599 us; speedup 1.0000x reference)
//
#include <hip/hip_runtime.h>
#include <hip/hip_bf16.h>

typedef __attribute__((ext_vector_type(8))) short short8;
typedef __attribute__((ext_vector_type(4))) float f32x4;

#define MFMA_BF16_16x16x32(a,b,c) __builtin_amdgcn_mfma_f32_16x16x32_bf16((a),(b),(c),0,0,0)

// Problem constants
constexpr int B_  = 4;
constexpr int S_  = 2048;
constexpr int H_  = 16;
constexpr int DH_ = 64;
constexpr int D_  = 1024;
constexpr int M_  = B_ * S_;

__device__ __forceinline__ unsigned short f2bf(float f) {
  union { float f; unsigned u; } v; v.f = f;
  unsigned u = v.u;
  u += 0x7fffu + ((u >> 16) & 1u);   // RNE
  return (unsigned short)(u >> 16);
}

__device__ __forceinline__ short8 cvt8(f32x4 a, f32x4 b) {
  union { __hip_bfloat162 h[4]; short8 s; } u;
  u.h[0] = __float22bfloat162_rn(make_float2(a[0], a[1]));
  u.h[1] = __float22bfloat162_rn(make_float2(a[2], a[3]));
  u.h[2] = __float22bfloat162_rn(make_float2(b[0], b[1]));
  u.h[3] = __float22bfloat162_rn(make_float2(b[2], b[3]));
  return u.s;
}

__device__ __forceinline__ unsigned pk2(float a, float b) {
  union { __hip_bfloat162 h; unsigned u; } z;
  z.h = __float22bfloat162_rn(make_float2(a, b));
  return z.u;
}

// ---------------------------------------------------------------------------
// Fused pre-conversion: x (4096 blocks) + Kw + Vw (512 each) in ONE dispatch.
// ---------------------------------------------------------------------------
__global__ __launch_bounds__(256)
void cvt_pre(const float* __restrict__ x, unsigned short* __restrict__ xb,
             const float* __restrict__ Kw, const float* __restrict__ Vw,
             unsigned short* __restrict__ Kwb, unsigned short* __restrict__ Vwb) {
  const int bb = blockIdx.x;
  const float* s;
  unsigned short* d;
  size_t i;
  if (bb < 4096)      { s = x;  d = xb;  i = ((size_t)bb * 256 + threadIdx.x) * 8; }
  else if (bb < 4608) { s = Kw; d = Kwb; i = ((size_t)(bb - 4096) * 256 + threadIdx.x) * 8; }
  else                { s = Vw; d = Vwb; i = ((size_t)(bb - 4608) * 256 + threadIdx.x) * 8; }
  *(short8*)(d + i) = cvt8(*(const f32x4*)(s + i), *(const f32x4*)(s + i + 4));
}

__global__ __launch_bounds__(256)
void cvt_w(const float* __restrict__ s0, unsigned short* __restrict__ d0) {
  const size_t i = ((size_t)blockIdx.x * 256 + threadIdx.x) * 8;
  *(short8*)(d0 + i) = cvt8(*(const f32x4*)(s0 + i), *(const f32x4*)(s0 + i + 4));
}

// ---------------------------------------------------------------------------
// global -> LDS staging, 16 B per lane (m97 ladder step 3).  LDS dest is
// wave-uniform base + lane*16, tile layout LINEAR [128][32] bf16.
// ---------------------------------------------------------------------------
__device__ __forceinline__ void stage16(const unsigned short* __restrict__ g,
                                        short* lds_wave_base, int lane) {
#if __has_builtin(__builtin_amdgcn_global_load_lds)
  __builtin_amdgcn_global_load_lds(
      (const __attribute__((address_space(1))) unsigned int*)g,
      (__attribute__((address_space(3))) unsigned int*)lds_wave_base, 16, 0, 0);
#else
  *(short8*)(lds_wave_base + lane * 8) = *(const short8*)g;
#endif
}

// ---------------------------------------------------------------------------
// gemm_bb: both operands bf16, 128x128 tile, BK=32, global_load_lds staging.
//   haveQ=0: nb 0..15 -> K, V only (production path).
// ---------------------------------------------------------------------------
__global__ __launch_bounds__(256)
void gemm_bb(const unsigned short* __restrict__ xb,
             const unsigned short* __restrict__ Qwb,
             const unsigned short* __restrict__ Kwb,
             const unsigned short* __restrict__ Vwb,
             unsigned short* __restrict__ Qo, unsigned short* __restrict__ Ko,
             unsigned short* __restrict__ VTo, int haveQ) {
  __shared__ __align__(16) short As[128 * 32];
  __shared__ __align__(16) short Bs[128 * 32];

  const int nb  = blockIdx.x;
  const int sel = haveQ ? (nb >> 3) : 1 + (nb >> 3);   // 0=Q 1=K 2=V
  const int n0  = (nb & 7) * 128;
  const unsigned short* Wb = (sel == 0) ? Qwb : (sel == 1) ? Kwb : Vwb;
  unsigned short* out      = (sel == 0) ? Qo  : (sel == 1) ? Ko  : VTo;
  const float scale = (sel == 0) ? 0.125f : 1.0f;
  const int epi = (sel == 2) ? 2 : 1;

  const int tid  = threadIdx.x;
  const int lane = tid & 63;
  const int w    = tid >> 6;
  const int quad = lane >> 4;
  const int l16  = lane & 15;
  const int wm   = (w >> 1) * 64;
  const int wn   = (w & 1) * 64;
  const int m0   = blockIdx.y * 128;

  const int srow = tid >> 2;
  const int scol = (tid & 3) * 8;

  f32x4 acc[4][4];
  #pragma unroll
  for (int i = 0; i < 4; ++i)
    #pragma unroll
    for (int j = 0; j < 4; ++j)
      acc[i][j] = (f32x4){0.f, 0.f, 0.f, 0.f};

  for (int k0 = 0; k0 < D_; k0 += 32) {
    __syncthreads();
    #pragma unroll
    for (int j = 0; j < 2; ++j) {
      const int row = j * 64 + srow;
      stage16(xb + (size_t)(m0 + row) * D_ + k0 + scol, As + j * 2048 + w * 512, lane);
      stage16(Wb + (size_t)(n0 + row) * D_ + k0 + scol, Bs + j * 2048 + w * 512, lane);
    }
    __syncthreads();

    short8 af[4], bf[4];
    #pragma unroll
    for (int i = 0; i < 4; ++i)
      af[i] = *(const short8*)(&As[(wm + i * 16 + l16) * 32 + quad * 8]);
    #pragma unroll
    for (int j = 0; j < 4; ++j)
      bf[j] = *(const short8*)(&Bs[(wn + j * 16 + l16) * 32 + quad * 8]);
    #pragma unroll
    for (int i = 0; i < 4; ++i)
      #pragma unroll
      for (int j = 0; j < 4; ++j)
        acc[i][j] = MFMA_BF16_16x16x32(af[i], bf[j], acc[i][j]);
  }

  #pragma unroll
  for (int i = 0; i < 4; ++i)
    #pragma unroll
    for (int j = 0; j < 4; ++j)
      #pragma unroll
      for (int r = 0; r < 4; ++r) {
        int m = m0 + wm + i * 16 + quad * 4 + r;
        int n = n0 + wn + j * 16 + l16;
        unsigned short bv = f2bf(acc[i][j][r] * scale);
        int b = m >> 11, s = m & (S_ - 1);
        int h = n >> 6,  d = n & (DH_ - 1);
        if (epi == 1)
          out[((size_t)(b * H_ + h) * S_ + s) * DH_ + d] = bv;
        else
          out[((size_t)(b * H_ + h) * DH_ + d) * S_ + s] = bv;
      }
}

// ---------------------------------------------------------------------------
// gemm_out_bb: CTX bf16 x Owb bf16 -> f32, same m97 structure.
// ---------------------------------------------------------------------------
__global__ __launch_bounds__(256)
void gemm_out_bb(const unsigned short* __restrict__ A,
                 const unsigned short* __restrict__ Wb,
                 float* __restrict__ out) {
  __shared__ __align__(16) short As[128 * 32];
  __shared__ __align__(16) short Bs[128 * 32];

  const int tid  = threadIdx.x;
  const int lane = tid & 63;
  const int w    = tid >> 6;
  const int quad = lane >> 4;
  const int l16  = lane & 15;
  const int wm   = (w >> 1) * 64;
  const int wn   = (w & 1) * 64;
  const int m0   = blockIdx.y * 128;
  const int n0   = blockIdx.x * 128;

  const int srow = tid >> 2;
  const int scol = (tid & 3) * 8;

  f32x4 acc[4][4];
  #pragma unroll
  for (int i = 0; i < 4; ++i)
    #pragma unroll
    for (int j = 0; j < 4; ++j)
      acc[i][j] = (f32x4){0.f, 0.f, 0.f, 0.f};

  for (int k0 = 0; k0 < D_; k0 += 32) {
    __syncthreads();
    #pragma unroll
    for (int j = 0; j < 2; ++j) {
      const int row = j * 64 + srow;
      stage16(A  + (size_t)(m0 + row) * D_ + k0 + scol, As + j * 2048 + w * 512, lane);
      stage16(Wb + (size_t)(n0 + row) * D_ + k0 + scol, Bs + j * 2048 + w * 512, lane);
    }
    __syncthreads();

    short8 af[4], bf[4];
    #pragma unroll
    for (int i = 0; i < 4; ++i)
      af[i] = *(const short8*)(&As[(wm + i * 16 + l16) * 32 + quad * 8]);
    #pragma unroll
    for (int j = 0; j < 4; ++j)
      bf[j] = *(const short8*)(&Bs[(wn + j * 16 + l16) * 32 + quad * 8]);
    #pragma unroll
    for (int i = 0; i < 4; ++i)
      #pragma unroll
      for (int j = 0; j < 4; ++j)
        acc[i][j] = MFMA_BF16_16x16x32(af[i], bf[j], acc[i][j]);
  }

  #pragma unroll
  for (int i = 0; i < 4; ++i)
    #pragma unroll
    for (int j = 0; j < 4; ++j)
      #pragma unroll
      for (int r = 0; r < 4; ++r) {
        int m = m0 + wm + i * 16 + quad * 4 + r;
        int n = n0 + wn + j * 16 + l16;
        out[(size_t)m * D_ + n] = acc[i][j][r];
      }
}

// ---------------------------------------------------------------------------
// gemm_q_f32w: Q projection, f32 W cvt8 on the fly (no memory slot exists for
// a bf16 Qw: d_out+ws = exactly xb+Q+K+VT, zero slack).
// ---------------------------------------------------------------------------
__global__ __launch_bounds__(256)
void gemm_q_f32w(const unsigned short* __restrict__ xb,
                 const float* __restrict__ Qw,
                 unsigned short* __restrict__ Qo) {
  constexpr int LDK = 40;
  __shared__ __align__(16) short As[128 * LDK];
  __shared__ __align__(16) short Bs[128 * LDK];

  const int tid  = threadIdx.x;
  const int lane = tid & 63;
  const int w    = tid >> 6;
  const int quad = lane >> 4;
  const int l16  = lane & 15;
  const int wm   = (w >> 1) * 64;
  const int wn   = (w & 1) * 64;
  const int m0   = blockIdx.y * 128;
  const int n0   = blockIdx.x * 128;

  f32x4 acc[4][4];
  #pragma unroll
  for (int i = 0; i < 4; ++i)
    #pragma unroll
    for (int j = 0; j < 4; ++j)
      acc[i][j] = (f32x4){0.f, 0.f, 0.f, 0.f};

  for (int k0 = 0; k0 < D_; k0 += 32) {
    __syncthreads();
    #pragma unroll
    for (int i = 0; i < 2; ++i) {
      int flat = i * 256 + tid;
      int row  = flat >> 2;
      int col  = (flat & 3) * 8;
      *(short8*)(&As[row * LDK + col]) =
          *(const short8*)(xb + (size_t)(m0 + row) * D_ + k0 + col);
      const float* Wp = Qw + (size_t)(n0 + row) * D_ + k0 + col;
      *(short8*)(&Bs[row * LDK + col]) = cvt8(*(const f32x4*)Wp, *(const f32x4*)(Wp + 4));
    }
    __syncthreads();

    short8 af[4], bf[4];
    #pragma unroll
    for (int i = 0; i < 4; ++i)
      af[i] = *(const short8*)(&As[(wm + i * 16 + l16) * LDK + quad * 8]);
    #pragma unroll
    for (int j = 0; j < 4; ++j)
      bf[j] = *(const short8*)(&Bs[(wn + j * 16 + l16) * LDK + quad * 8]);
    #pragma unroll
    for (int i = 0; i < 4; ++i)
      #pragma unroll
      for (int j = 0; j < 4; ++j)
        acc[i][j] = MFMA_BF16_16x16x32(af[i], bf[j], acc[i][j]);
  }

  #pragma unroll
  for (int i = 0; i < 4; ++i)
    #pragma unroll
    for (int j = 0; j < 4; ++j)
      #pragma unroll
      for (int r = 0; r < 4; ++r) {
        int m = m0 + wm + i * 16 + quad * 4 + r;
        int n = n0 + wn + j * 16 + l16;
        unsigned short bv = f2bf(acc[i][j][r] * 0.125f);
        int b = m >> 11, s = m & (S_ - 1);
        int h = n >> 6,  d = n & (DH_ - 1);
        Qo[((size_t)(b * H_ + h) * S_ + s) * DH_ + d] = bv;
      }
}

// ---------------------------------------------------------------------------
// MFMA flash attention R17: K-prefetch + CORRECT column-XOR P swizzle.
//
// R16 failed: XOR of bits 4-6 applied to the FULL byte address with row
// stride 144B (not a multiple of 128) -> non-bijective (e.g. (r0,b128) and
// (r1,b0) both -> phys 128) -> P corruption (absmax 468).  Fix derived from
// the bijectivity rule: all P accesses have col-byte < 128, so use LINEAR
// row stride 128B (LDP=64, no pad) and XOR ONLY the column offset:
//   addr = row*128 + (col ^ ((row&7)<<4)),  col in [0,128)  -> bijective.
// Writer key (row = i*16+l16 -> l16&7) == reader keys (rows l16, 16+l16).
// Bank math: writes = 4 lanes per 2-bank slot (uniform optimum for 8B x64);
// reads = 8 lanes per 4-bank slot (uniform optimum for 16B x64). Conflict-
// free both ways -- strictly better than R15's padded layout.
// K-prefetch (kept from R16, logic verified): next tile's K loaded into the
// same kb[8] after sc dies; prologue covers kt0; clamp on last iter.
// ---------------------------------------------------------------------------
constexpr int LDP_ = 64;

__device__ __forceinline__ void attn_range(
    const unsigned short* __restrict__ Kh,
    const unsigned short* __restrict__ Vh,
    const unsigned char* __restrict__ pmb,
    short* __restrict__ Pw,
    const short8 qf[2][2], f32x4 acc[2][4], f32x4 lacc[2],
    int qw, int kt0, int kt1, int quad, int l16) {
  const short8 ones = {0x3F80, 0x3F80, 0x3F80, 0x3F80,
                       0x3F80, 0x3F80, 0x3F80, 0x3F80};   // bf16 1.0 x8
  if (kt0 >= kt1) return;
  const int key = (l16 & 7) << 4;   // column-XOR key, bits 4-6 (byte units)

  // prologue: K fragments for the first tile
  short8 kb[8];
  {
    const int k0 = kt0 * 64;
    #pragma unroll
    for (int t = 0; t < 4; ++t) {
      const unsigned short* kp = Kh + (size_t)(k0 + t * 16 + l16) * DH_ + quad * 8;
      kb[t * 2]     = *(const short8*)(kp);
      kb[t * 2 + 1] = *(const short8*)(kp + 32);
    }
  }

  for (int kt = kt0; kt < kt1; ++kt) {
    const int k0 = kt * 64;

    unsigned pm4[4];
    #pragma unroll
    for (int t = 0; t < 4; ++t)
      pm4[t] = *(const unsigned*)(pmb + k0 + t * 16 + quad * 4);

    // ---- swapped QK^T: D[key][q]; lane holds keys quad*4+r of q-row l16 ----
    f32x4 sc[2][4];
    __builtin_amdgcn_s_setprio(1);
    #pragma unroll
    for (int t = 0; t < 4; ++t) {
      #pragma unroll
      for (int i = 0; i < 2; ++i) {
        f32x4 z = (f32x4){0.f, 0.f, 0.f, 0.f};
        z = MFMA_BF16_16x16x32(kb[t * 2], qf[i][0], z);
        sc[i][t] = MFMA_BF16_16x16x32(kb[t * 2 + 1], qf[i][1], z);
      }
    }
    __builtin_amdgcn_s_setprio(0);

    // V ks=0 half: latency hides under exp/pack
    short8 vb[8];
    #pragma unroll
    for (int t = 0; t < 4; ++t)
      vb[t] = *(const short8*)(Vh + (size_t)(t * 16 + l16) * S_ + k0 + quad * 8);

    // static-max softmax: P = exp(sc), masked -> 0
    #pragma unroll
    for (int i = 0; i < 2; ++i)
      #pragma unroll
      for (int t = 0; t < 4; ++t)
        #pragma unroll
        for (int r = 0; r < 4; ++r) {
          float e = __expf(sc[i][t][r]);
          sc[i][t][r] = ((pm4[t] >> (8 * r)) & 0xffu) ? 0.f : e;
        }
    if (k0 + 63 > qw) {
      #pragma unroll
      for (int t = 0; t < 4; ++t)
        #pragma unroll
        for (int r = 0; r < 4; ++r) {
          int kk = k0 + t * 16 + quad * 4 + r;
          #pragma unroll
          for (int i = 0; i < 2; ++i) {
            int qrow = qw + i * 16 + l16;
            if (kk > qrow) sc[i][t][r] = 0.f;
          }
        }
    }

    // pack + swizzled P store: 8 x ds_write_b64 (col-XOR, bijective per row)
    #pragma unroll
    for (int i = 0; i < 2; ++i)
      #pragma unroll
      for (int t = 0; t < 4; ++t) {
        unsigned lo = pk2(sc[i][t][0], sc[i][t][1]);
        unsigned hi = pk2(sc[i][t][2], sc[i][t][3]);
        int boff = (i * 16 + l16) * 128 + ((t * 32 + quad * 8) ^ key);
        *(uint2*)((char*)Pw + boff) = make_uint2(lo, hi);
      }

    // ---- prefetch NEXT tile's K into the same kb regs (sc now dead) ----
    asm volatile("" ::: "memory");
    {
      const int kn = (kt + 1 < kt1) ? (kt + 1) * 64 : k0;   // clamp: safe reload
      #pragma unroll
      for (int t = 0; t < 4; ++t) {
        const unsigned short* kp = Kh + (size_t)(kn + t * 16 + l16) * DH_ + quad * 8;
        kb[t * 2]     = *(const short8*)(kp);
        kb[t * 2 + 1] = *(const short8*)(kp + 32);
      }
    }

    // V ks=1 half
    #pragma unroll
    for (int t = 0; t < 4; ++t)
      vb[4 + t] = *(const short8*)(Vh + (size_t)(t * 16 + l16) * S_ + k0 + 32 + quad * 8);

    // PV + ones-MFMA rowsum (swizzled pa reads, same per-row key)
    __builtin_amdgcn_s_setprio(1);
    #pragma unroll
    for (int ks = 0; ks < 2; ++ks) {
      short8 pa0 = *(const short8*)((const char*)Pw +
                    (l16 * 128 + ((ks * 64 + quad * 16) ^ key)));
      short8 pa1 = *(const short8*)((const char*)Pw +
                    ((16 + l16) * 128 + ((ks * 64 + quad * 16) ^ key)));
      #pragma unroll
      for (int t = 0; t < 4; ++t) {
        acc[0][t] = MFMA_BF16_16x16x32(pa0, vb[ks * 4 + t], acc[0][t]);
        acc[1][t] = MFMA_BF16_16x16x32(pa1, vb[ks * 4 + t], acc[1][t]);
      }
      lacc[0] = MFMA_BF16_16x16x32(pa0, ones, lacc[0]);
      lacc[1] = MFMA_BF16_16x16x32(pa1, ones, lacc[1]);
    }
    __builtin_amdgcn_s_setprio(0);
  }
}

__global__ __launch_bounds__(128)
void attn(const unsigned short* __restrict__ Q,
          const unsigned short* __restrict__ K,
          const unsigned short* __restrict__ VT,
          const unsigned char* __restrict__ pmask,
          unsigned short* __restrict__ CTX) {
  __shared__ __align__(16) short Ps[2 * 32 * LDP_];   // 8 KB
  __shared__ float Rbuf[64 * 40];                     // 10.2 KB

  const int tid  = threadIdx.x;
  const int lane = tid & 63;
  const int w    = tid >> 6;
  const int quad = lane >> 4;
  const int l16  = lane & 15;

  const int L    = blockIdx.x;
  const int xcd  = L & 7;
  const int slot = L >> 3;
  const int bh   = xcd + 8 * (slot & 7);
  const int p    = slot >> 3;
  const int b    = bh >> 4;
  const int h    = bh & 15;

  const int qtA = p, qtB = 63 - p;
  const int ntA = (qtA >> 1) + 1;
  const int ntB = (qtB >> 1) + 1;
  const int splitB = 17 - ntA;

  const unsigned short* Qh = Q  + ((size_t)b * H_ + h) * S_ * DH_;
  const unsigned short* Kh = K  + ((size_t)b * H_ + h) * S_ * DH_;
  const unsigned short* Vh = VT + ((size_t)b * H_ + h) * DH_ * S_;
  const unsigned char* pmb = pmask + (size_t)b * S_;
  unsigned short* CTXb = CTX + (size_t)b * S_ * D_;
  short* Pw = &Ps[w * 32 * LDP_];

  f32x4 acc[2][4];
  f32x4 lacc[2];
  short8 qf[2][2];

  if (w == 0) {
    {
      const int qw = qtA * 32;
      #pragma unroll
      for (int i = 0; i < 2; ++i)
        #pragma unroll
        for (int c = 0; c < 2; ++c)
          qf[i][c] = *(const short8*)(Qh + (size_t)(qw + i * 16 + l16) * DH_ + c * 32 + quad * 8);
      #pragma unroll
      for (int i = 0; i < 2; ++i) {
        #pragma unroll
        for (int t = 0; t < 4; ++t) acc[i][t] = (f32x4){0.f, 0.f, 0.f, 0.f};
        lacc[i] = (f32x4){0.f, 0.f, 0.f, 0.f};
      }
      attn_range(Kh, Vh, pmb, Pw, qf, acc, lacc, qw, 0, ntA, quad, l16);
      #pragma unroll
      for (int i = 0; i < 2; ++i)
        #pragma unroll
        for (int r = 0; r < 4; ++r) {
          int qrow = qw + i * 16 + quad * 4 + r;
          float inv = 1.0f / lacc[i][r];
          #pragma unroll
          for (int t = 0; t < 4; ++t)
            CTXb[(size_t)qrow * D_ + h * DH_ + t * 16 + l16] = f2bf(acc[i][t][r] * inv);
        }
    }
    {
      const int qw = qtB * 32;
      #pragma unroll
      for (int i = 0; i < 2; ++i)
        #pragma unroll
        for (int c = 0; c < 2; ++c)
          qf[i][c] = *(const short8*)(Qh + (size_t)(qw + i * 16 + l16) * DH_ + c * 32 + quad * 8);
      #pragma unroll
      for (int i = 0; i < 2; ++i) {
        #pragma unroll
        for (int t = 0; t < 4; ++t) acc[i][t] = (f32x4){0.f, 0.f, 0.f, 0.f};
        lacc[i] = (f32x4){0.f, 0.f, 0.f, 0.f};
      }
      attn_range(Kh, Vh, pmb, Pw, qf, acc, lacc, qw, 0, splitB, quad, l16);
      __syncthreads();
      #pragma unroll
      for (int i = 0; i < 2; ++i) {
        #pragma unroll
        for (int t = 0; t < 4; ++t)
          #pragma unroll
          for (int r = 0; r < 4; ++r)
            acc[i][t][r] += Rbuf[lane * 40 + i * 16 + t * 4 + r];
        #pragma unroll
        for (int r = 0; r < 4; ++r)
          lacc[i][r] += Rbuf[lane * 40 + 32 + i * 4 + r];
      }
      #pragma unroll
      for (int i = 0; i < 2; ++i)
        #pragma unroll
        for (int r = 0; r < 4; ++r) {
          int qrow = qw + i * 16 + quad * 4 + r;
          float inv = 1.0f / lacc[i][r];
          #pragma unroll
          for (int t = 0; t < 4; ++t)
            CTXb[(size_t)qrow * D_ + h * DH_ + t * 16 + l16] = f2bf(acc[i][t][r] * inv);
        }
    }
  } else {
    const int qw = qtB * 32;
    #pragma unroll
    for (int i = 0; i < 2; ++i)
      #pragma unroll
      for (int c = 0; c < 2; ++c)
        qf[i][c] = *(const short8*)(Qh + (size_t)(qw + i * 16 + l16) * DH_ + c * 32 + quad * 8);
    #pragma unroll
    for (int i = 0; i < 2; ++i) {
      #pragma unroll
      for (int t = 0; t < 4; ++t) acc[i][t] = (f32x4){0.f, 0.f, 0.f, 0.f};
      lacc[i] = (f32x4){0.f, 0.f, 0.f, 0.f};
    }
    attn_range(Kh, Vh, pmb, Pw, qf, acc, lacc, qw, splitB, ntB, quad, l16);
    #pragma unroll
    for (int i = 0; i < 2; ++i) {
      #pragma unroll
      for (int t = 0; t < 4; ++t)
        #pragma unroll
        for (int r = 0; r < 4; ++r)
          Rbuf[lane * 40 + i * 16 + t * 4 + r] = acc[i][t][r];
      #pragma unroll
      for (int r = 0; r < 4; ++r)
        Rbuf[lane * 40 + 32 + i * 4 + r] = lacc[i][r];
    }
    __syncthreads();
  }
}

// ---------------------------------------------------------------------------
// R17 schedule (no-tail memory plan, zero slack):
//   d_out: [Qall 16.8M][xb->CTX 16.8M]   ws: [Kall 16.8M][VTall 16.8M]
//   Kwb/Vwb scratch in dead Qall region; K/V via gemm_bb; Q via f32-W path;
//   Owb overwrites VTall after attn.
// ---------------------------------------------------------------------------
extern "C" void kernel_launch(void* const* d_in, const int* in_sizes, int n_in,
                              void* d_out, int out_size, void* d_ws, size_t ws_size,
                              hipStream_t stream) {
  const float* x  = (const float*)d_in[0];
  const float* Qw = (const float*)d_in[1];
  const float* Kw = (const float*)d_in[2];
  const float* Vw = (const float*)d_in[3];
  const float* Ow = (const float*)d_in[4];
  const unsigned char* pm = (const unsigned char*)d_in[5];

  const size_t NE = (size_t)M_ * D_;
  const size_t DD = (size_t)D_ * D_;
  unsigned short* Qall  = (unsigned short*)d_out;
  unsigned short* CTXa  = (unsigned short*)d_out + NE;   // xb first, CTX later
  unsigned short* ws16  = (unsigned short*)d_ws;
  unsigned short* Kall  = ws16;
  unsigned short* VTall = ws16 + NE;
  unsigned short* Owb   = VTall;                         // after attn

  unsigned short* Kwb = Qall;            // scratch in dead Qall region
  unsigned short* Vwb = Qall + DD;

  cvt_pre<<<dim3(4096 + 1024), 256, 0, stream>>>(x, CTXa, Kw, Vw, Kwb, Vwb);

  gemm_bb<<<dim3(16, M_ / 128), 256, 0, stream>>>(CTXa, nullptr, Kwb, Vwb,
                                                  Qall, Kall, VTall, 0);
  gemm_q_f32w<<<dim3(8, M_ / 128), 256, 0, stream>>>(CTXa, Qw, Qall);

  attn<<<dim3(2048), 128, 0, stream>>>(Qall, Kall, VTall, pm, CTXa);

  cvt_w<<<dim3(512), 256, 0, stream>>>(Ow, Owb);

  hipMemcpyAsync(d_ws, (const void*)CTXa, NE * sizeof(unsigned short),
                 hipMemcpyDeviceToDevice, stream);

  gemm_out_bb<<<dim3(D_ / 128, M_ / 128), 256, 0, stream>>>(ws16, Owb,
                                                            (float*)d_out);
}

// Round 10
// 343.737 us; speedup vs baseline: 1.1014x; 1.1014x over previous
//
#include <hip/hip_runtime.h>
#include <hip/hip_bf16.h>

typedef __attribute__((ext_vector_type(8))) short short8;
typedef __attribute__((ext_vector_type(4))) float f32x4;

#define MFMA_BF16_16x16x32(a,b,c) __builtin_amdgcn_mfma_f32_16x16x32_bf16((a),(b),(c),0,0,0)

// Problem constants
constexpr int B_  = 4;
constexpr int S_  = 2048;
constexpr int H_  = 16;
constexpr int DH_ = 64;
constexpr int D_  = 1024;
constexpr int M_  = B_ * S_;

__device__ __forceinline__ unsigned short f2bf(float f) {
  union { float f; unsigned u; } v; v.f = f;
  unsigned u = v.u;
  u += 0x7fffu + ((u >> 16) & 1u);   // RNE
  return (unsigned short)(u >> 16);
}

__device__ __forceinline__ short8 cvt8(f32x4 a, f32x4 b) {
  union { __hip_bfloat162 h[4]; short8 s; } u;
  u.h[0] = __float22bfloat162_rn(make_float2(a[0], a[1]));
  u.h[1] = __float22bfloat162_rn(make_float2(a[2], a[3]));
  u.h[2] = __float22bfloat162_rn(make_float2(b[0], b[1]));
  u.h[3] = __float22bfloat162_rn(make_float2(b[2], b[3]));
  return u.s;
}

__device__ __forceinline__ unsigned pk2(float a, float b) {
  union { __hip_bfloat162 h; unsigned u; } z;
  z.h = __float22bfloat162_rn(make_float2(a, b));
  return z.u;
}

// ---------------------------------------------------------------------------
// Fused pre-conversion: x (4096 blocks) + up to 4 weight matrices (512 blocks
// each).  Tail path converts all of {Qw,Kw,Vw,Ow} here -> 1 dispatch total.
// ---------------------------------------------------------------------------
__global__ __launch_bounds__(256)
void cvt_many(const float* __restrict__ x,  unsigned short* __restrict__ xb,
              const float* __restrict__ s1, unsigned short* __restrict__ d1,
              const float* __restrict__ s2, unsigned short* __restrict__ d2,
              const float* __restrict__ s3, unsigned short* __restrict__ d3,
              const float* __restrict__ s4, unsigned short* __restrict__ d4) {
  const int bb = blockIdx.x;
  const float* s;
  unsigned short* d;
  size_t i;
  if (bb < 4096) { s = x; d = xb; i = ((size_t)bb * 256 + threadIdx.x) * 8; }
  else {
    const int a = (bb - 4096) >> 9;
    const int r = (bb - 4096) & 511;
    s = (a == 0) ? s1 : (a == 1) ? s2 : (a == 2) ? s3 : s4;
    d = (a == 0) ? d1 : (a == 1) ? d2 : (a == 2) ? d3 : d4;
    i = ((size_t)r * 256 + threadIdx.x) * 8;
  }
  *(short8*)(d + i) = cvt8(*(const f32x4*)(s + i), *(const f32x4*)(s + i + 4));
}

__global__ __launch_bounds__(256)
void cvt_w(const float* __restrict__ s0, unsigned short* __restrict__ d0) {
  const size_t i = ((size_t)blockIdx.x * 256 + threadIdx.x) * 8;
  *(short8*)(d0 + i) = cvt8(*(const f32x4*)(s0 + i), *(const f32x4*)(s0 + i + 4));
}

// ---------------------------------------------------------------------------
// global -> LDS staging, 16 B per lane (m97 ladder step 3).  LDS dest is
// wave-uniform base + lane*16, tile layout LINEAR [128][32] bf16.
// ---------------------------------------------------------------------------
__device__ __forceinline__ void stage16(const unsigned short* __restrict__ g,
                                        short* lds_wave_base, int lane) {
#if __has_builtin(__builtin_amdgcn_global_load_lds)
  __builtin_amdgcn_global_load_lds(
      (const __attribute__((address_space(1))) unsigned int*)g,
      (__attribute__((address_space(3))) unsigned int*)lds_wave_base, 16, 0, 0);
#else
  *(short8*)(lds_wave_base + lane * 8) = *(const short8*)g;
#endif
}

// ---------------------------------------------------------------------------
// gemm_bb: both operands bf16, 128x128 tile, BK=32, global_load_lds staging.
//   haveQ=1: nb 0..23 -> Q,K,V (tail path).  haveQ=0: nb 0..15 -> K,V.
// ---------------------------------------------------------------------------
__global__ __launch_bounds__(256)
void gemm_bb(const unsigned short* __restrict__ xb,
             const unsigned short* __restrict__ Qwb,
             const unsigned short* __restrict__ Kwb,
             const unsigned short* __restrict__ Vwb,
             unsigned short* __restrict__ Qo, unsigned short* __restrict__ Ko,
             unsigned short* __restrict__ VTo, int haveQ) {
  __shared__ __align__(16) short As[128 * 32];
  __shared__ __align__(16) short Bs[128 * 32];

  const int nb  = blockIdx.x;
  const int sel = haveQ ? (nb >> 3) : 1 + (nb >> 3);   // 0=Q 1=K 2=V
  const int n0  = (nb & 7) * 128;
  const unsigned short* Wb = (sel == 0) ? Qwb : (sel == 1) ? Kwb : Vwb;
  unsigned short* out      = (sel == 0) ? Qo  : (sel == 1) ? Ko  : VTo;
  const float scale = (sel == 0) ? 0.125f : 1.0f;
  const int epi = (sel == 2) ? 2 : 1;

  const int tid  = threadIdx.x;
  const int lane = tid & 63;
  const int w    = tid >> 6;
  const int quad = lane >> 4;
  const int l16  = lane & 15;
  const int wm   = (w >> 1) * 64;
  const int wn   = (w & 1) * 64;
  const int m0   = blockIdx.y * 128;

  const int srow = tid >> 2;
  const int scol = (tid & 3) * 8;

  f32x4 acc[4][4];
  #pragma unroll
  for (int i = 0; i < 4; ++i)
    #pragma unroll
    for (int j = 0; j < 4; ++j)
      acc[i][j] = (f32x4){0.f, 0.f, 0.f, 0.f};

  for (int k0 = 0; k0 < D_; k0 += 32) {
    __syncthreads();
    #pragma unroll
    for (int j = 0; j < 2; ++j) {
      const int row = j * 64 + srow;
      stage16(xb + (size_t)(m0 + row) * D_ + k0 + scol, As + j * 2048 + w * 512, lane);
      stage16(Wb + (size_t)(n0 + row) * D_ + k0 + scol, Bs + j * 2048 + w * 512, lane);
    }
    __syncthreads();

    short8 af[4], bf[4];
    #pragma unroll
    for (int i = 0; i < 4; ++i)
      af[i] = *(const short8*)(&As[(wm + i * 16 + l16) * 32 + quad * 8]);
    #pragma unroll
    for (int j = 0; j < 4; ++j)
      bf[j] = *(const short8*)(&Bs[(wn + j * 16 + l16) * 32 + quad * 8]);
    #pragma unroll
    for (int i = 0; i < 4; ++i)
      #pragma unroll
      for (int j = 0; j < 4; ++j)
        acc[i][j] = MFMA_BF16_16x16x32(af[i], bf[j], acc[i][j]);
  }

  #pragma unroll
  for (int i = 0; i < 4; ++i)
    #pragma unroll
    for (int j = 0; j < 4; ++j)
      #pragma unroll
      for (int r = 0; r < 4; ++r) {
        int m = m0 + wm + i * 16 + quad * 4 + r;
        int n = n0 + wn + j * 16 + l16;
        unsigned short bv = f2bf(acc[i][j][r] * scale);
        int b = m >> 11, s = m & (S_ - 1);
        int h = n >> 6,  d = n & (DH_ - 1);
        if (epi == 1)
          out[((size_t)(b * H_ + h) * S_ + s) * DH_ + d] = bv;
        else
          out[((size_t)(b * H_ + h) * DH_ + d) * S_ + s] = bv;
      }
}

// ---------------------------------------------------------------------------
// gemm_out_bb: CTX bf16 x Owb bf16 -> f32, same m97 structure.
// ---------------------------------------------------------------------------
__global__ __launch_bounds__(256)
void gemm_out_bb(const unsigned short* __restrict__ A,
                 const unsigned short* __restrict__ Wb,
                 float* __restrict__ out) {
  __shared__ __align__(16) short As[128 * 32];
  __shared__ __align__(16) short Bs[128 * 32];

  const int tid  = threadIdx.x;
  const int lane = tid & 63;
  const int w    = tid >> 6;
  const int quad = lane >> 4;
  const int l16  = lane & 15;
  const int wm   = (w >> 1) * 64;
  const int wn   = (w & 1) * 64;
  const int m0   = blockIdx.y * 128;
  const int n0   = blockIdx.x * 128;

  const int srow = tid >> 2;
  const int scol = (tid & 3) * 8;

  f32x4 acc[4][4];
  #pragma unroll
  for (int i = 0; i < 4; ++i)
    #pragma unroll
    for (int j = 0; j < 4; ++j)
      acc[i][j] = (f32x4){0.f, 0.f, 0.f, 0.f};

  for (int k0 = 0; k0 < D_; k0 += 32) {
    __syncthreads();
    #pragma unroll
    for (int j = 0; j < 2; ++j) {
      const int row = j * 64 + srow;
      stage16(A  + (size_t)(m0 + row) * D_ + k0 + scol, As + j * 2048 + w * 512, lane);
      stage16(Wb + (size_t)(n0 + row) * D_ + k0 + scol, Bs + j * 2048 + w * 512, lane);
    }
    __syncthreads();

    short8 af[4], bf[4];
    #pragma unroll
    for (int i = 0; i < 4; ++i)
      af[i] = *(const short8*)(&As[(wm + i * 16 + l16) * 32 + quad * 8]);
    #pragma unroll
    for (int j = 0; j < 4; ++j)
      bf[j] = *(const short8*)(&Bs[(wn + j * 16 + l16) * 32 + quad * 8]);
    #pragma unroll
    for (int i = 0; i < 4; ++i)
      #pragma unroll
      for (int j = 0; j < 4; ++j)
        acc[i][j] = MFMA_BF16_16x16x32(af[i], bf[j], acc[i][j]);
  }

  #pragma unroll
  for (int i = 0; i < 4; ++i)
    #pragma unroll
    for (int j = 0; j < 4; ++j)
      #pragma unroll
      for (int r = 0; r < 4; ++r) {
        int m = m0 + wm + i * 16 + quad * 4 + r;
        int n = n0 + wn + j * 16 + l16;
        out[(size_t)m * D_ + n] = acc[i][j][r];
      }
}

// ---------------------------------------------------------------------------
// gemm_q_f32w: Q projection fallback (no-tail plan has zero slack for a
// bf16 Qw): bf16 A from xb, f32 W cvt8 on the fly, LDK=40 padded LDS.
// ---------------------------------------------------------------------------
__global__ __launch_bounds__(256)
void gemm_q_f32w(const unsigned short* __restrict__ xb,
                 const float* __restrict__ Qw,
                 unsigned short* __restrict__ Qo) {
  constexpr int LDK = 40;
  __shared__ __align__(16) short As[128 * LDK];
  __shared__ __align__(16) short Bs[128 * LDK];

  const int tid  = threadIdx.x;
  const int lane = tid & 63;
  const int w    = tid >> 6;
  const int quad = lane >> 4;
  const int l16  = lane & 15;
  const int wm   = (w >> 1) * 64;
  const int wn   = (w & 1) * 64;
  const int m0   = blockIdx.y * 128;
  const int n0   = blockIdx.x * 128;

  f32x4 acc[4][4];
  #pragma unroll
  for (int i = 0; i < 4; ++i)
    #pragma unroll
    for (int j = 0; j < 4; ++j)
      acc[i][j] = (f32x4){0.f, 0.f, 0.f, 0.f};

  for (int k0 = 0; k0 < D_; k0 += 32) {
    __syncthreads();
    #pragma unroll
    for (int i = 0; i < 2; ++i) {
      int flat = i * 256 + tid;
      int row  = flat >> 2;
      int col  = (flat & 3) * 8;
      *(short8*)(&As[row * LDK + col]) =
          *(const short8*)(xb + (size_t)(m0 + row) * D_ + k0 + col);
      const float* Wp = Qw + (size_t)(n0 + row) * D_ + k0 + col;
      *(short8*)(&Bs[row * LDK + col]) = cvt8(*(const f32x4*)Wp, *(const f32x4*)(Wp + 4));
    }
    __syncthreads();

    short8 af[4], bf[4];
    #pragma unroll
    for (int i = 0; i < 4; ++i)
      af[i] = *(const short8*)(&As[(wm + i * 16 + l16) * LDK + quad * 8]);
    #pragma unroll
    for (int j = 0; j < 4; ++j)
      bf[j] = *(const short8*)(&Bs[(wn + j * 16 + l16) * LDK + quad * 8]);
    #pragma unroll
    for (int i = 0; i < 4; ++i)
      #pragma unroll
      for (int j = 0; j < 4; ++j)
        acc[i][j] = MFMA_BF16_16x16x32(af[i], bf[j], acc[i][j]);
  }

  #pragma unroll
  for (int i = 0; i < 4; ++i)
    #pragma unroll
    for (int j = 0; j < 4; ++j)
      #pragma unroll
      for (int r = 0; r < 4; ++r) {
        int m = m0 + wm + i * 16 + quad * 4 + r;
        int n = n0 + wn + j * 16 + l16;
        unsigned short bv = f2bf(acc[i][j][r] * 0.125f);
        int b = m >> 11, s = m & (S_ - 1);
        int h = n >> 6,  d = n & (DH_ - 1);
        Qo[((size_t)(b * H_ + h) * S_ + s) * DH_ + d] = bv;
      }
}

// ---------------------------------------------------------------------------
// MFMA flash attention R18: split-K pairs, swapped QK^T, static-max softmax,
// col-XOR P swizzle (R17, proven), Rbuf padded to stride 41.
//
// R17 post-mortem: K-prefetch was NET-NEGATIVE (+8 VGPR, +4MB redundant
// FETCH, attn 143.9->148.9) -> reverted.  Residual 2.4M bank conflicts
// traced to Rbuf: float[64*40], stride 40 floats -> lane*40 % 32 puts 64
// lanes on 4 banks (8-way) for the partial-sum exchange.  Pad to 41.
// ---------------------------------------------------------------------------
constexpr int LDP_ = 64;

__device__ __forceinline__ void attn_range(
    const unsigned short* __restrict__ Kh,
    const unsigned short* __restrict__ Vh,
    const unsigned char* __restrict__ pmb,
    short* __restrict__ Pw,
    const short8 qf[2][2], f32x4 acc[2][4], f32x4 lacc[2],
    int qw, int kt0, int kt1, int quad, int l16) {
  const short8 ones = {0x3F80, 0x3F80, 0x3F80, 0x3F80,
                       0x3F80, 0x3F80, 0x3F80, 0x3F80};   // bf16 1.0 x8
  const int key = (l16 & 7) << 4;   // column-XOR key, bits 4-6 (byte units)

  for (int kt = kt0; kt < kt1; ++kt) {
    const int k0 = kt * 64;

    // K fragments for this tile (8 x b128 from L2)
    short8 kb[8];
    #pragma unroll
    for (int t = 0; t < 4; ++t) {
      const unsigned short* kp = Kh + (size_t)(k0 + t * 16 + l16) * DH_ + quad * 8;
      kb[t * 2]     = *(const short8*)(kp);
      kb[t * 2 + 1] = *(const short8*)(kp + 32);
    }
    unsigned pm4[4];
    #pragma unroll
    for (int t = 0; t < 4; ++t)
      pm4[t] = *(const unsigned*)(pmb + k0 + t * 16 + quad * 4);

    // ---- swapped QK^T: D[key][q]; lane holds keys quad*4+r of q-row l16 ----
    f32x4 sc[2][4];
    __builtin_amdgcn_s_setprio(1);
    #pragma unroll
    for (int t = 0; t < 4; ++t) {
      #pragma unroll
      for (int i = 0; i < 2; ++i) {
        f32x4 z = (f32x4){0.f, 0.f, 0.f, 0.f};
        z = MFMA_BF16_16x16x32(kb[t * 2], qf[i][0], z);
        sc[i][t] = MFMA_BF16_16x16x32(kb[t * 2 + 1], qf[i][1], z);
      }
    }
    __builtin_amdgcn_s_setprio(0);

    // V ks=0 half: latency hides under exp/pack
    short8 vb[8];
    #pragma unroll
    for (int t = 0; t < 4; ++t)
      vb[t] = *(const short8*)(Vh + (size_t)(t * 16 + l16) * S_ + k0 + quad * 8);

    // static-max softmax: P = exp(sc), masked -> 0
    #pragma unroll
    for (int i = 0; i < 2; ++i)
      #pragma unroll
      for (int t = 0; t < 4; ++t)
        #pragma unroll
        for (int r = 0; r < 4; ++r) {
          float e = __expf(sc[i][t][r]);
          sc[i][t][r] = ((pm4[t] >> (8 * r)) & 0xffu) ? 0.f : e;
        }
    if (k0 + 63 > qw) {
      #pragma unroll
      for (int t = 0; t < 4; ++t)
        #pragma unroll
        for (int r = 0; r < 4; ++r) {
          int kk = k0 + t * 16 + quad * 4 + r;
          #pragma unroll
          for (int i = 0; i < 2; ++i) {
            int qrow = qw + i * 16 + l16;
            if (kk > qrow) sc[i][t][r] = 0.f;
          }
        }
    }

    // pack + swizzled P store: 8 x ds_write_b64 (col-XOR, bijective per row)
    #pragma unroll
    for (int i = 0; i < 2; ++i)
      #pragma unroll
      for (int t = 0; t < 4; ++t) {
        unsigned lo = pk2(sc[i][t][0], sc[i][t][1]);
        unsigned hi = pk2(sc[i][t][2], sc[i][t][3]);
        int boff = (i * 16 + l16) * 128 + ((t * 32 + quad * 8) ^ key);
        *(uint2*)((char*)Pw + boff) = make_uint2(lo, hi);
      }

    // V ks=1 half
    #pragma unroll
    for (int t = 0; t < 4; ++t)
      vb[4 + t] = *(const short8*)(Vh + (size_t)(t * 16 + l16) * S_ + k0 + 32 + quad * 8);

    // PV + ones-MFMA rowsum (swizzled pa reads, same per-row key)
    __builtin_amdgcn_s_setprio(1);
    #pragma unroll
    for (int ks = 0; ks < 2; ++ks) {
      short8 pa0 = *(const short8*)((const char*)Pw +
                    (l16 * 128 + ((ks * 64 + quad * 16) ^ key)));
      short8 pa1 = *(const short8*)((const char*)Pw +
                    ((16 + l16) * 128 + ((ks * 64 + quad * 16) ^ key)));
      #pragma unroll
      for (int t = 0; t < 4; ++t) {
        acc[0][t] = MFMA_BF16_16x16x32(pa0, vb[ks * 4 + t], acc[0][t]);
        acc[1][t] = MFMA_BF16_16x16x32(pa1, vb[ks * 4 + t], acc[1][t]);
      }
      lacc[0] = MFMA_BF16_16x16x32(pa0, ones, lacc[0]);
      lacc[1] = MFMA_BF16_16x16x32(pa1, ones, lacc[1]);
    }
    __builtin_amdgcn_s_setprio(0);
  }
}

__global__ __launch_bounds__(128)
void attn(const unsigned short* __restrict__ Q,
          const unsigned short* __restrict__ K,
          const unsigned short* __restrict__ VT,
          const unsigned char* __restrict__ pmask,
          unsigned short* __restrict__ CTX) {
  __shared__ __align__(16) short Ps[2 * 32 * LDP_];   // 8 KB
  __shared__ float Rbuf[64 * 41];                     // 10.5 KB, stride-41 pad

  const int tid  = threadIdx.x;
  const int lane = tid & 63;
  const int w    = tid >> 6;
  const int quad = lane >> 4;
  const int l16  = lane & 15;

  const int L    = blockIdx.x;
  const int xcd  = L & 7;
  const int slot = L >> 3;
  const int bh   = xcd + 8 * (slot & 7);
  const int p    = slot >> 3;
  const int b    = bh >> 4;
  const int h    = bh & 15;

  const int qtA = p, qtB = 63 - p;
  const int ntA = (qtA >> 1) + 1;
  const int ntB = (qtB >> 1) + 1;
  const int splitB = 17 - ntA;

  const unsigned short* Qh = Q  + ((size_t)b * H_ + h) * S_ * DH_;
  const unsigned short* Kh = K  + ((size_t)b * H_ + h) * S_ * DH_;
  const unsigned short* Vh = VT + ((size_t)b * H_ + h) * DH_ * S_;
  const unsigned char* pmb = pmask + (size_t)b * S_;
  unsigned short* CTXb = CTX + (size_t)b * S_ * D_;
  short* Pw = &Ps[w * 32 * LDP_];

  f32x4 acc[2][4];
  f32x4 lacc[2];
  short8 qf[2][2];

  if (w == 0) {
    {
      const int qw = qtA * 32;
      #pragma unroll
      for (int i = 0; i < 2; ++i)
        #pragma unroll
        for (int c = 0; c < 2; ++c)
          qf[i][c] = *(const short8*)(Qh + (size_t)(qw + i * 16 + l16) * DH_ + c * 32 + quad * 8);
      #pragma unroll
      for (int i = 0; i < 2; ++i) {
        #pragma unroll
        for (int t = 0; t < 4; ++t) acc[i][t] = (f32x4){0.f, 0.f, 0.f, 0.f};
        lacc[i] = (f32x4){0.f, 0.f, 0.f, 0.f};
      }
      attn_range(Kh, Vh, pmb, Pw, qf, acc, lacc, qw, 0, ntA, quad, l16);
      #pragma unroll
      for (int i = 0; i < 2; ++i)
        #pragma unroll
        for (int r = 0; r < 4; ++r) {
          int qrow = qw + i * 16 + quad * 4 + r;
          float inv = 1.0f / lacc[i][r];
          #pragma unroll
          for (int t = 0; t < 4; ++t)
            CTXb[(size_t)qrow * D_ + h * DH_ + t * 16 + l16] = f2bf(acc[i][t][r] * inv);
        }
    }
    {
      const int qw = qtB * 32;
      #pragma unroll
      for (int i = 0; i < 2; ++i)
        #pragma unroll
        for (int c = 0; c < 2; ++c)
          qf[i][c] = *(const short8*)(Qh + (size_t)(qw + i * 16 + l16) * DH_ + c * 32 + quad * 8);
      #pragma unroll
      for (int i = 0; i < 2; ++i) {
        #pragma unroll
        for (int t = 0; t < 4; ++t) acc[i][t] = (f32x4){0.f, 0.f, 0.f, 0.f};
        lacc[i] = (f32x4){0.f, 0.f, 0.f, 0.f};
      }
      attn_range(Kh, Vh, pmb, Pw, qf, acc, lacc, qw, 0, splitB, quad, l16);
      __syncthreads();
      #pragma unroll
      for (int i = 0; i < 2; ++i) {
        #pragma unroll
        for (int t = 0; t < 4; ++t)
          #pragma unroll
          for (int r = 0; r < 4; ++r)
            acc[i][t][r] += Rbuf[lane * 41 + i * 16 + t * 4 + r];
        #pragma unroll
        for (int r = 0; r < 4; ++r)
          lacc[i][r] += Rbuf[lane * 41 + 32 + i * 4 + r];
      }
      #pragma unroll
      for (int i = 0; i < 2; ++i)
        #pragma unroll
        for (int r = 0; r < 4; ++r) {
          int qrow = qw + i * 16 + quad * 4 + r;
          float inv = 1.0f / lacc[i][r];
          #pragma unroll
          for (int t = 0; t < 4; ++t)
            CTXb[(size_t)qrow * D_ + h * DH_ + t * 16 + l16] = f2bf(acc[i][t][r] * inv);
        }
    }
  } else {
    const int qw = qtB * 32;
    #pragma unroll
    for (int i = 0; i < 2; ++i)
      #pragma unroll
      for (int c = 0; c < 2; ++c)
        qf[i][c] = *(const short8*)(Qh + (size_t)(qw + i * 16 + l16) * DH_ + c * 32 + quad * 8);
    #pragma unroll
    for (int i = 0; i < 2; ++i) {
      #pragma unroll
      for (int t = 0; t < 4; ++t) acc[i][t] = (f32x4){0.f, 0.f, 0.f, 0.f};
      lacc[i] = (f32x4){0.f, 0.f, 0.f, 0.f};
    }
    attn_range(Kh, Vh, pmb, Pw, qf, acc, lacc, qw, splitB, ntB, quad, l16);
    #pragma unroll
    for (int i = 0; i < 2; ++i) {
      #pragma unroll
      for (int t = 0; t < 4; ++t)
        #pragma unroll
        for (int r = 0; r < 4; ++r)
          Rbuf[lane * 41 + i * 16 + t * 4 + r] = acc[i][t][r];
      #pragma unroll
      for (int r = 0; r < 4; ++r)
        Rbuf[lane * 41 + 32 + i * 4 + r] = lacc[i][r];
    }
    __syncthreads();
  }
}

// ---------------------------------------------------------------------------
// R18 schedule.
//   d_out: [Qall 16.8M][xb->CTX 16.8M]   ws: [Kall 16.8M][VTall 16.8M](+tail?)
// tail path (ws_size >= (2NE+4DD)*2): Qwb/Kwb/Vwb/Owb at ws tail ->
//   cvt_many(x+4W) -> gemm_bb(24) -> attn -> memcpy -> gemm_out.  5 dispatches,
//   Q at bf16-GEMM speed.
// no-tail: Kwb/Vwb scratch in dead Qall region; K/V via gemm_bb(16); Q via
//   f32-W path; Owb overwrites VTall after attn.  7 dispatches.
// ---------------------------------------------------------------------------
extern "C" void kernel_launch(void* const* d_in, const int* in_sizes, int n_in,
                              void* d_out, int out_size, void* d_ws, size_t ws_size,
                              hipStream_t stream) {
  const float* x  = (const float*)d_in[0];
  const float* Qw = (const float*)d_in[1];
  const float* Kw = (const float*)d_in[2];
  const float* Vw = (const float*)d_in[3];
  const float* Ow = (const float*)d_in[4];
  const unsigned char* pm = (const unsigned char*)d_in[5];

  const size_t NE = (size_t)M_ * D_;
  const size_t DD = (size_t)D_ * D_;
  unsigned short* Qall  = (unsigned short*)d_out;
  unsigned short* CTXa  = (unsigned short*)d_out + NE;   // xb first, CTX later
  unsigned short* ws16  = (unsigned short*)d_ws;
  unsigned short* Kall  = ws16;
  unsigned short* VTall = ws16 + NE;

  const bool tail = ws_size >= (2 * NE + 4 * DD) * sizeof(unsigned short);

  if (tail) {
    unsigned short* Qwb = ws16 + 2 * NE;
    unsigned short* Kwb = Qwb + DD;
    unsigned short* Vwb = Kwb + DD;
    unsigned short* Owb = Vwb + DD;

    cvt_many<<<dim3(4096 + 4 * 512), 256, 0, stream>>>(
        x, CTXa, Qw, Qwb, Kw, Kwb, Vw, Vwb, Ow, Owb);

    gemm_bb<<<dim3(24, M_ / 128), 256, 0, stream>>>(CTXa, Qwb, Kwb, Vwb,
                                                    Qall, Kall, VTall, 1);

    attn<<<dim3(2048), 128, 0, stream>>>(Qall, Kall, VTall, pm, CTXa);

    hipMemcpyAsync(d_ws, (const void*)CTXa, NE * sizeof(unsigned short),
                   hipMemcpyDeviceToDevice, stream);

    gemm_out_bb<<<dim3(D_ / 128, M_ / 128), 256, 0, stream>>>(ws16, Owb,
                                                              (float*)d_out);
  } else {
    unsigned short* Kwb = Qall;            // scratch in dead Qall region
    unsigned short* Vwb = Qall + DD;
    unsigned short* Owb = VTall;           // after attn

    cvt_many<<<dim3(4096 + 2 * 512), 256, 0, stream>>>(
        x, CTXa, Kw, Kwb, Vw, Vwb, Vw, Vwb, Vw, Vwb);

    gemm_bb<<<dim3(16, M_ / 128), 256, 0, stream>>>(CTXa, nullptr, Kwb, Vwb,
                                                    Qall, Kall, VTall, 0);
    gemm_q_f32w<<<dim3(8, M_ / 128), 256, 0, stream>>>(CTXa, Qw, Qall);

    attn<<<dim3(2048), 128, 0, stream>>>(Qall, Kall, VTall, pm, CTXa);

    cvt_w<<<dim3(512), 256, 0, stream>>>(Ow, Owb);

    hipMemcpyAsync(d_ws, (const void*)CTXa, NE * sizeof(unsigned short),
                   hipMemcpyDeviceToDevice, stream);

    gemm_out_bb<<<dim3(D_ / 128, M_ / 128), 256, 0, stream>>>(ws16, Owb,
                                                              (float*)d_out);
  }
}